// Round 2
// baseline (363.699 us; speedup 1.0000x reference)
//
#include <hip/hip_runtime.h>

// cdist(x1, x2) on MI355X: d[i][j] = sqrt(||x1_i||^2 + ||x2_j||^2 - 2*x1_i.x2_j)
// R2: K=256 is too small for the m97 LDS-staged structure (4 k-iters, 8 full
// vmcnt(0) barrier drains dominated). Load MFMA fragments DIRECTLY from global
// (L2-served 64B row segments), no LDS, no barriers. Output stores nontemporal
// to keep the 8 MiB bf16 inputs L2-resident.

typedef __bf16 v8bf __attribute__((ext_vector_type(8)));
typedef float v4f __attribute__((ext_vector_type(4)));

#define NROWS 8192
#define KDIM  256
#define TILE  128   // block tile: 128x128, 4 waves, each 64x64

__device__ __forceinline__ ushort f2bf_rne(float f) {
    union { float f; unsigned u; } a; a.f = f;
    unsigned u = a.u + 0x7fffu + ((a.u >> 16) & 1u);  // round-to-nearest-even
    return (ushort)(u >> 16);
}

// One wave per row: load 256 floats as float4/lane, emit bf16 row + fp32 norm.
__global__ __launch_bounds__(256) void cvt_norm_kernel(
    const float* __restrict__ x, ushort* __restrict__ xb, float* __restrict__ sq) {
    const int wave = threadIdx.x >> 6;
    const int lane = threadIdx.x & 63;
    const int row  = blockIdx.x * 4 + wave;
    const float4 v = ((const float4*)(x + (size_t)row * KDIM))[lane];
    float s = v.x * v.x + v.y * v.y + v.z * v.z + v.w * v.w;
#pragma unroll
    for (int off = 32; off; off >>= 1) s += __shfl_down(s, off);
    if (lane == 0) sq[row] = s;
    ushort4 o;
    o.x = f2bf_rne(v.x); o.y = f2bf_rne(v.y);
    o.z = f2bf_rne(v.z); o.w = f2bf_rne(v.w);
    ((ushort4*)(xb + (size_t)row * KDIM))[lane] = o;
}

__global__ __launch_bounds__(256) void cdist_mfma_kernel(
    const ushort* __restrict__ A,    // x1 bf16, [8192][256]
    const ushort* __restrict__ B,    // x2 bf16, [8192][256]
    const float* __restrict__ sq1,   // ||x1_i||^2
    const float* __restrict__ sq2,   // ||x2_j||^2
    float* __restrict__ out) {       // [8192][8192]
    const int bm = blockIdx.x, bn = blockIdx.y;
    const int tid  = threadIdx.x;
    const int wave = tid >> 6;
    const int lane = tid & 63;
    const int wr = wave >> 1;         // wave tile row (0..1) -> 64 rows of A
    const int wc = wave & 1;          // wave tile col (0..1) -> 64 rows of B

    const int half = lane >> 4;       // 0..3: selects k-subgroup (8 bf16 each)
    const int mrow = lane & 15;       // fragment row within 16

    // A fragment for 16x16x32: lane reads A[row = base+mrow][k = kt + half*8 .. +8]
    // = 16B contiguous, 16 rows x 64B segments per instruction. Same for B
    // (row-major [n][k] feeds the B operand directly — verified in R1).
    const ushort* a_base =
        A + (size_t)(bm * TILE + wr * 64 + mrow) * KDIM + half * 8;
    const ushort* b_base =
        B + (size_t)(bn * TILE + wc * 64 + mrow) * KDIM + half * 8;

    v4f acc[4][4];
#pragma unroll
    for (int i = 0; i < 4; ++i)
#pragma unroll
        for (int j = 0; j < 4; ++j) acc[i][j] = (v4f){0.f, 0.f, 0.f, 0.f};

    // K-loop: 8 iterations, no LDS, no barriers. Per iter: 8 dwordx4 loads
    // (immediate k offsets) + 16 MFMAs. ILP + occupancy hide L2 latency.
#pragma unroll
    for (int kt = 0; kt < KDIM; kt += 32) {
        v8bf a[4], b[4];
#pragma unroll
        for (int i = 0; i < 4; ++i)
            a[i] = *(const v8bf*)(a_base + (size_t)i * 16 * KDIM + kt);
#pragma unroll
        for (int i = 0; i < 4; ++i)
            b[i] = *(const v8bf*)(b_base + (size_t)i * 16 * KDIM + kt);
#pragma unroll
        for (int i = 0; i < 4; ++i)
#pragma unroll
            for (int j = 0; j < 4; ++j)
                acc[i][j] = __builtin_amdgcn_mfma_f32_16x16x32_bf16(
                    a[i], b[j], acc[i][j], 0, 0, 0);
    }

    // Epilogue: C/D layout col=lane&15, row=(lane>>4)*4+reg (m89/m91 verified).
    // Nontemporal stores: 256 MiB streams straight out, inputs stay in L2.
    const int m0 = bm * TILE + wr * 64;
    const int n0 = bn * TILE + wc * 64;
    float s2[4];
#pragma unroll
    for (int j = 0; j < 4; ++j) s2[j] = sq2[n0 + j * 16 + mrow];
#pragma unroll
    for (int i = 0; i < 4; ++i) {
#pragma unroll
        for (int r = 0; r < 4; ++r) {
            const int row = m0 + i * 16 + half * 4 + r;
            const float s1 = sq1[row];
            float* orow = out + (size_t)row * NROWS + n0 + mrow;
#pragma unroll
            for (int j = 0; j < 4; ++j) {
                const float d2 = s1 + s2[j] - 2.0f * acc[i][j][r];
                __builtin_nontemporal_store(sqrtf(fmaxf(d2, 0.0f)),
                                            orow + j * 16);
            }
        }
    }
}

extern "C" void kernel_launch(void* const* d_in, const int* in_sizes, int n_in,
                              void* d_out, int out_size, void* d_ws, size_t ws_size,
                              hipStream_t stream) {
    const float* x1 = (const float*)d_in[0];
    const float* x2 = (const float*)d_in[1];
    float* out = (float*)d_out;

    // ws layout: A_bf16 (4 MiB) | B_bf16 (4 MiB) | sq1 (32 KiB) | sq2 (32 KiB)
    ushort* Ab = (ushort*)d_ws;
    ushort* Bb = Ab + (size_t)NROWS * KDIM;
    float* sq1 = (float*)(Bb + (size_t)NROWS * KDIM);
    float* sq2 = sq1 + NROWS;

    cvt_norm_kernel<<<NROWS / 4, 256, 0, stream>>>(x1, Ab, sq1);
    cvt_norm_kernel<<<NROWS / 4, 256, 0, stream>>>(x2, Bb, sq2);

    dim3 grid(NROWS / TILE, NROWS / TILE);  // 64 x 64
    cdist_mfma_kernel<<<grid, 256, 0, stream>>>(Ab, Bb, sq1, sq2, out);
}